// Round 12
// baseline (1299.326 us; speedup 1.0000x reference)
//
#include <hip/hip_runtime.h>
#include <cstdint>
#include <cstddef>

typedef __bf16 bf16;
typedef __attribute__((ext_vector_type(4))) __bf16 bf16x4;
typedef __attribute__((ext_vector_type(8))) __bf16 bf16x8;
typedef __attribute__((ext_vector_type(4))) float floatx4;

#define MFMA16(a,b,c) __builtin_amdgcn_mfma_f32_16x16x32_bf16(a,b,c,0,0,0)

__device__ __forceinline__ float sigmf_(float x){ return 1.f/(1.f+expf(-x)); }
__device__ __forceinline__ float eluf_(float x){ return x>0.f ? x : (expf(x)-1.f); }

// ---------------------------------------------------------------------------
// MFMA GEMM: C[M,N] = epi(A[M,K] @ B^T[N,K]) ; A fp32 (cvt->bf16), BT bf16.
// Block 256 thr, tile 128x64, BK=64, swizzled LDS (byte ^= (row&7)<<4).
// EPI: 0 none, 1 +bias, 2 elu(+bias), 3 +bias2(split@128), 4 +bias+resid
// ---------------------------------------------------------------------------
template<int EPI>
__global__ void __launch_bounds__(256, 2)
gemm_bf16(const float* __restrict__ A, int lda,
          const bf16* __restrict__ BT, int ldb,
          float* __restrict__ C, int ldc,
          const float* __restrict__ b1, const float* __restrict__ b2r,
          int K)
{
  __shared__ char sm[16384 + 8192];
  const int tid = threadIdx.x;
  const int bm = blockIdx.y * 128, bn = blockIdx.x * 64;
  const int l = tid & 63, w = tid >> 6;
  const int wm = (w >> 1) * 64, wn = (w & 1) * 32;
  floatx4 acc[4][2];
  #pragma unroll
  for (int i = 0; i < 4; ++i)
    #pragma unroll
    for (int j = 0; j < 2; ++j)
      #pragma unroll
      for (int r = 0; r < 4; ++r) acc[i][j][r] = 0.f;

  for (int k0 = 0; k0 < K; k0 += 64) {
    {
      int r0 = tid >> 4, kq = (tid & 15) * 4;
      #pragma unroll
      for (int p = 0; p < 8; ++p) {
        int m = r0 + p * 16;
        float4 v = *(const float4*)(A + (size_t)(bm + m) * lda + k0 + kq);
        bf16x4 hv; hv[0]=(bf16)v.x; hv[1]=(bf16)v.y; hv[2]=(bf16)v.z; hv[3]=(bf16)v.w;
        unsigned off = ((unsigned)(m * 128 + kq * 2)) ^ ((unsigned)(m & 7) << 4);
        *(bf16x4*)(sm + off) = hv;
      }
      int n = tid >> 2, c = (tid & 3) * 16;
      const bf16* src = BT + (size_t)(bn + n) * ldb + k0 + c;
      bf16x8 v0 = *(const bf16x8*)(src);
      bf16x8 v1 = *(const bf16x8*)(src + 8);
      unsigned o0 = 16384u + (((unsigned)(n * 128 + c * 2))      ^ ((unsigned)(n & 7) << 4));
      unsigned o1 = 16384u + (((unsigned)(n * 128 + c * 2 + 16)) ^ ((unsigned)(n & 7) << 4));
      *(bf16x8*)(sm + o0) = v0;
      *(bf16x8*)(sm + o1) = v1;
    }
    __syncthreads();
    const int row = l & 15, kb = (l >> 4) * 8;
    #pragma unroll
    for (int kk = 0; kk < 64; kk += 32) {
      bf16x8 a[4], b[2];
      #pragma unroll
      for (int i = 0; i < 4; ++i) {
        int m = wm + i * 16 + row;
        unsigned off = ((unsigned)(m * 128 + (kk + kb) * 2)) ^ ((unsigned)(m & 7) << 4);
        a[i] = *(const bf16x8*)(sm + off);
      }
      #pragma unroll
      for (int j = 0; j < 2; ++j) {
        int n = wn + j * 16 + row;
        unsigned off = 16384u + (((unsigned)(n * 128 + (kk + kb) * 2)) ^ ((unsigned)(n & 7) << 4));
        b[j] = *(const bf16x8*)(sm + off);
      }
      #pragma unroll
      for (int i = 0; i < 4; ++i)
        #pragma unroll
        for (int j = 0; j < 2; ++j)
          acc[i][j] = MFMA16(a[i], b[j], acc[i][j]);
    }
    __syncthreads();
  }
  #pragma unroll
  for (int i = 0; i < 4; ++i)
    #pragma unroll
    for (int j = 0; j < 2; ++j)
      #pragma unroll
      for (int r = 0; r < 4; ++r) {
        int grow = bm + wm + i * 16 + ((l >> 4) << 2) + r;
        int gcol = bn + wn + j * 16 + (l & 15);
        float v = acc[i][j][r];
        if (EPI == 1) v += b1[gcol];
        else if (EPI == 2) { v += b1[gcol]; v = eluf_(v); }
        else if (EPI == 3) { v += (gcol < 128) ? b1[gcol] : b2r[gcol - 128]; }
        else if (EPI == 4) { v += b1[gcol] + b2r[(size_t)grow * ldc + gcol]; }
        C[(size_t)grow * ldc + gcol] = v;
      }
}

// ---------------------------------------------------------------------------
// 64x64 transpose+cvt tile helper (fp32 src -> bf16 dst, dst = src^T)
// ---------------------------------------------------------------------------
__device__ __forceinline__ void tile_tr64(const float* __restrict__ src, int srcld,
                                          bf16* __restrict__ dst, int dstld,
                                          float (*ld)[72])
{
  const int tid = threadIdx.x;
  const int r = tid >> 2, q = tid & 3;
  #pragma unroll
  for (int i = 0; i < 4; ++i) {
    int col = q * 16 + i * 4;
    *(float4*)&ld[r][col] = *(const float4*)(src + (size_t)r * srcld + col);
  }
  __syncthreads();
  bf16x8 o0, o1;
  #pragma unroll
  for (int i = 0; i < 8; ++i) o0[i] = (bf16)ld[q * 16 + i][r];
  #pragma unroll
  for (int i = 0; i < 8; ++i) o1[i] = (bf16)ld[q * 16 + 8 + i][r];
  *(bf16x8*)(dst + (size_t)r * dstld + q * 16) = o0;
  *(bf16x8*)(dst + (size_t)r * dstld + q * 16 + 8) = o1;
}

__global__ void __launch_bounds__(256)
transpose_sv(const float* __restrict__ w2, const float* __restrict__ wo,
             const float* __restrict__ wg, bf16* __restrict__ svT)
{
  __shared__ float ld[64][72];
  int mat = blockIdx.y >> 7;
  int f = blockIdx.y & 127;
  const float* src = (mat == 0 ? w2 : (mat == 1 ? wo : wg)) + (size_t)f * 65536;
  bf16* dst = svT + (size_t)blockIdx.y * 65536;
  int tc = blockIdx.x & 3, tr = blockIdx.x >> 2;
  tile_tr64(src + (size_t)(tr * 64) * 256 + tc * 64, 256,
            dst + (size_t)(tc * 64) * 256 + tr * 64, 256, ld);
}

struct TJob { const float* src; bf16* dst; int R; int C; };
struct TJobs { TJob j[22]; };

__global__ void __launch_bounds__(256)
transpose_misc(TJobs jobs)
{
  __shared__ float ld[64][72];
  TJob J = jobs.j[blockIdx.y];
  int ntc = J.C >> 6;
  int tiles = (J.R >> 6) * ntc;
  if ((int)blockIdx.x >= tiles) return;
  int tc = blockIdx.x % ntc, tr = blockIdx.x / ntc;
  tile_tr64(J.src + (size_t)(tr * 64) * J.C + tc * 64, J.C,
            J.dst + (size_t)(tc * 64) * J.R + tr * 64, J.R, ld);
}

// fp32 -> bf16 convert of 4 lstm weight matrices (each 262144 elems)
__global__ void __launch_bounds__(256)
cvt4_kernel(const float* __restrict__ s0, const float* __restrict__ s1,
            const float* __restrict__ s2, const float* __restrict__ s3,
            bf16* __restrict__ dst)
{
  size_t i = ((size_t)blockIdx.x * 256 + threadIdx.x) * 4;
  int mat = (int)(i >> 18);
  const float* s = (mat == 0) ? s0 : (mat == 1) ? s1 : (mat == 2) ? s2 : s3;
  float4 v = *(const float4*)(s + (i & 262143));
  bf16x4 o; o[0]=(bf16)v.x; o[1]=(bf16)v.y; o[2]=(bf16)v.z; o[3]=(bf16)v.w;
  *(bf16x4*)(dst + i) = o;
}

// ---------------------------------------------------------------------------
// GRN-flat combine: pre = sigmoid(g)*o + skip ; LN(128) ; softmax(128)
// ---------------------------------------------------------------------------
__global__ void __launch_bounds__(256, 4)
grnflat_sw_kernel(const float* __restrict__ go, const float* __restrict__ skip,
                  const float* __restrict__ lng, const float* __restrict__ lnb,
                  float* __restrict__ sw_out)
{
  const int tid = threadIdx.x;
  const int m = blockIdx.x * 4 + (tid >> 6);
  const int l = tid & 63, c = l * 2;
  float g0 = go[(size_t)m * 256 + c],       g1 = go[(size_t)m * 256 + c + 1];
  float o0 = go[(size_t)m * 256 + 128 + c], o1 = go[(size_t)m * 256 + 128 + c + 1];
  float sk0 = skip[(size_t)m * 128 + c],    sk1 = skip[(size_t)m * 128 + c + 1];
  float p0 = sigmf_(g0) * o0 + sk0;
  float p1 = sigmf_(g1) * o1 + sk1;
  float s = p0 + p1, s2 = p0 * p0 + p1 * p1;
  #pragma unroll
  for (int k = 1; k < 64; k <<= 1) { s += __shfl_xor(s, k, 64); s2 += __shfl_xor(s2, k, 64); }
  float mean = s * (1.f / 128.f);
  float var = s2 * (1.f / 128.f) - mean * mean;
  float rs = rsqrtf(var + 1e-5f);
  float t0 = (p0 - mean) * rs * lng[c] + lnb[c];
  float t1 = (p1 - mean) * rs * lng[c + 1] + lnb[c + 1];
  float mx = fmaxf(t0, t1);
  #pragma unroll
  for (int k = 1; k < 64; k <<= 1) mx = fmaxf(mx, __shfl_xor(mx, k, 64));
  float e0 = expf(t0 - mx), e1 = expf(t1 - mx);
  float se = e0 + e1;
  #pragma unroll
  for (int k = 1; k < 64; k <<= 1) se += __shfl_xor(se, k, 64);
  float inv = 1.f / se;
  float2 wv; wv.x = e0 * inv; wv.y = e1 * inv;
  *(float2*)(sw_out + (size_t)m * 128 + c) = wv;
}

// ---------------------------------------------------------------------------
// Per-variable GRN (MFMA): block = (feature f, 64-token tile). 512 thr, 8 waves.
// ---------------------------------------------------------------------------
__global__ void __launch_bounds__(512, 2)
pervar_kernel(const bf16* __restrict__ xT, const bf16* __restrict__ svT,
              const float* __restrict__ w1g, const float* __restrict__ b1g,
              const float* __restrict__ b2g, const float* __restrict__ bog,
              const float* __restrict__ bgg, const float* __restrict__ swg,
              const float* __restrict__ sbg, const float* __restrict__ lngg,
              const float* __restrict__ lnbg,
              bf16* __restrict__ vbuf, int f0)
{
  __shared__ char sm[65536];
  const int tid = threadIdx.x;
  const int fl = blockIdx.y, f = f0 + fl, tile = blockIdx.x;
  const int l = tid & 63, w = tid >> 6;
  const int wm = (w >> 2) * 32, wn = (w & 3) * 64;
  const int row = l & 15, kb = (l >> 4) * 8;
  const size_t fb = (size_t)f * 256;

  {
    int m = tid >> 3, ks8 = (tid & 7) * 32;
    float x = (float)xT[(size_t)f * 1024 + tile * 64 + m];
    #pragma unroll
    for (int i = 0; i < 4; ++i) {
      int k = ks8 + i * 8;
      float4 w0v = *(const float4*)(w1g + fb + k);
      float4 w1v = *(const float4*)(w1g + fb + k + 4);
      float4 b0v = *(const float4*)(b1g + fb + k);
      float4 b1v = *(const float4*)(b1g + fb + k + 4);
      bf16x8 hv;
      hv[0] = (bf16)eluf_(x * w0v.x + b0v.x);
      hv[1] = (bf16)eluf_(x * w0v.y + b0v.y);
      hv[2] = (bf16)eluf_(x * w0v.z + b0v.z);
      hv[3] = (bf16)eluf_(x * w0v.w + b0v.w);
      hv[4] = (bf16)eluf_(x * w1v.x + b1v.x);
      hv[5] = (bf16)eluf_(x * w1v.y + b1v.y);
      hv[6] = (bf16)eluf_(x * w1v.z + b1v.z);
      hv[7] = (bf16)eluf_(x * w1v.w + b1v.w);
      unsigned off = ((unsigned)(m * 512 + k * 2)) ^ ((unsigned)(m & 7) << 4);
      *(bf16x8*)(sm + off) = hv;
    }
  }

  auto stageB = [&](const bf16* BT, int ks) {
    int n = tid >> 1, c = (tid & 1) * 32;
    const bf16* src = BT + (size_t)n * 256 + ks * 64 + c;
    #pragma unroll
    for (int qq = 0; qq < 4; ++qq) {
      unsigned ro = (((unsigned)(n * 128 + (c + qq * 8) * 2)) ^ ((unsigned)(n & 7) << 4));
      *(bf16x8*)(sm + 32768 + ro) = *(const bf16x8*)(src + qq * 8);
    }
  };

  floatx4 acc1[2][4];
  #pragma unroll
  for (int i = 0; i < 2; ++i)
    #pragma unroll
    for (int j = 0; j < 4; ++j)
      #pragma unroll
      for (int r = 0; r < 4; ++r) acc1[i][j][r] = 0.f;
  const bf16* w2T = svT + (size_t)f * 65536;
  for (int ks = 0; ks < 4; ++ks) {
    __syncthreads();
    stageB(w2T, ks);
    __syncthreads();
    #pragma unroll
    for (int kk = 0; kk < 64; kk += 32) {
      int kloc = kk + kb;
      bf16x8 a[2], b[4];
      #pragma unroll
      for (int i = 0; i < 2; ++i) {
        int m = wm + i * 16 + row;
        unsigned off = ((unsigned)(m * 512 + (ks * 64 + kloc) * 2)) ^ ((unsigned)(m & 7) << 4);
        a[i] = *(const bf16x8*)(sm + off);
      }
      #pragma unroll
      for (int j = 0; j < 4; ++j) {
        int n = wn + j * 16 + row;
        unsigned off = 32768u + (((unsigned)(n * 128 + kloc * 2)) ^ ((unsigned)(n & 7) << 4));
        b[j] = *(const bf16x8*)(sm + off);
      }
      #pragma unroll
      for (int i = 0; i < 2; ++i)
        #pragma unroll
        for (int j = 0; j < 4; ++j)
          acc1[i][j] = MFMA16(a[i], b[j], acc1[i][j]);
    }
  }
  __syncthreads();
  #pragma unroll
  for (int i = 0; i < 2; ++i)
    #pragma unroll
    for (int j = 0; j < 4; ++j)
      #pragma unroll
      for (int r = 0; r < 4; ++r) {
        int m = wm + i * 16 + ((l >> 4) << 2) + r;
        int col = wn + j * 16 + (l & 15);
        float v = eluf_(acc1[i][j][r] + b2g[fb + col]);
        unsigned off = ((unsigned)(m * 512 + col * 2)) ^ ((unsigned)(m & 7) << 4);
        *(bf16*)(sm + off) = (bf16)v;
      }
  __syncthreads();

  floatx4 accO[2][4], accG[2][4];
  #pragma unroll
  for (int i = 0; i < 2; ++i)
    #pragma unroll
    for (int j = 0; j < 4; ++j)
      #pragma unroll
      for (int r = 0; r < 4; ++r) { accO[i][j][r] = 0.f; accG[i][j][r] = 0.f; }
  const bf16* woT = svT + ((size_t)128 + f) * 65536;
  const bf16* wgT = svT + ((size_t)256 + f) * 65536;
  for (int ks = 0; ks < 4; ++ks) {
    __syncthreads();
    stageB(woT, ks);
    __syncthreads();
    #pragma unroll
    for (int kk = 0; kk < 64; kk += 32) {
      int kloc = kk + kb;
      bf16x8 a[2], b[4];
      #pragma unroll
      for (int i = 0; i < 2; ++i) {
        int m = wm + i * 16 + row;
        unsigned off = ((unsigned)(m * 512 + (ks * 64 + kloc) * 2)) ^ ((unsigned)(m & 7) << 4);
        a[i] = *(const bf16x8*)(sm + off);
      }
      #pragma unroll
      for (int j = 0; j < 4; ++j) {
        int n = wn + j * 16 + row;
        unsigned off = 32768u + (((unsigned)(n * 128 + kloc * 2)) ^ ((unsigned)(n & 7) << 4));
        b[j] = *(const bf16x8*)(sm + off);
      }
      #pragma unroll
      for (int i = 0; i < 2; ++i)
        #pragma unroll
        for (int j = 0; j < 4; ++j)
          accO[i][j] = MFMA16(a[i], b[j], accO[i][j]);
    }
  }
  for (int ks = 0; ks < 4; ++ks) {
    __syncthreads();
    stageB(wgT, ks);
    __syncthreads();
    #pragma unroll
    for (int kk = 0; kk < 64; kk += 32) {
      int kloc = kk + kb;
      bf16x8 a[2], b[4];
      #pragma unroll
      for (int i = 0; i < 2; ++i) {
        int m = wm + i * 16 + row;
        unsigned off = ((unsigned)(m * 512 + (ks * 64 + kloc) * 2)) ^ ((unsigned)(m & 7) << 4);
        a[i] = *(const bf16x8*)(sm + off);
      }
      #pragma unroll
      for (int j = 0; j < 4; ++j) {
        int n = wn + j * 16 + row;
        unsigned off = 32768u + (((unsigned)(n * 128 + kloc * 2)) ^ ((unsigned)(n & 7) << 4));
        b[j] = *(const bf16x8*)(sm + off);
      }
      #pragma unroll
      for (int i = 0; i < 2; ++i)
        #pragma unroll
        for (int j = 0; j < 4; ++j)
          accG[i][j] = MFMA16(a[i], b[j], accG[i][j]);
    }
  }
  __syncthreads();
  {
    float xm[2][4];
    #pragma unroll
    for (int i = 0; i < 2; ++i)
      #pragma unroll
      for (int r = 0; r < 4; ++r) {
        int m = wm + i * 16 + ((l >> 4) << 2) + r;
        xm[i][r] = (float)xT[(size_t)f * 1024 + tile * 64 + m];
      }
    #pragma unroll
    for (int i = 0; i < 2; ++i)
      #pragma unroll
      for (int j = 0; j < 4; ++j)
        #pragma unroll
        for (int r = 0; r < 4; ++r) {
          int m = wm + i * 16 + ((l >> 4) << 2) + r;
          int col = wn + j * 16 + (l & 15);
          float vg = sigmf_(accG[i][j][r] + bgg[fb + col]);
          float vo = accO[i][j][r] + bog[fb + col];
          float pre = vg * vo + xm[i][r] * swg[fb + col] + sbg[fb + col];
          unsigned off = ((unsigned)(m * 512 + col * 2)) ^ ((unsigned)(m & 7) << 4);
          *(bf16*)(sm + off) = (bf16)pre;
        }
  }
  __syncthreads();
  {
    int m = tid >> 3, q = tid & 7;
    float vals[32];
    float s = 0.f, s2 = 0.f;
    #pragma unroll
    for (int i = 0; i < 4; ++i) {
      unsigned off = ((unsigned)(m * 512 + (q * 32 + i * 8) * 2)) ^ ((unsigned)(m & 7) << 4);
      bf16x8 hv = *(const bf16x8*)(sm + off);
      #pragma unroll
      for (int j = 0; j < 8; ++j) {
        float x = (float)hv[j];
        vals[i * 8 + j] = x; s += x; s2 += x * x;
      }
    }
    s += __shfl_xor(s, 1, 64);  s += __shfl_xor(s, 2, 64);  s += __shfl_xor(s, 4, 64);
    s2 += __shfl_xor(s2, 1, 64); s2 += __shfl_xor(s2, 2, 64); s2 += __shfl_xor(s2, 4, 64);
    float mean = s * (1.f / 256.f);
    float var = s2 * (1.f / 256.f) - mean * mean;
    float rs = rsqrtf(var + 1e-5f);
    bf16* dst = vbuf + ((size_t)fl * 1024 + tile * 64 + m) * 256 + q * 32;
    #pragma unroll
    for (int i = 0; i < 4; ++i) {
      int c = q * 32 + i * 8;
      float4 g0 = *(const float4*)(lngg + fb + c);
      float4 g1 = *(const float4*)(lngg + fb + c + 4);
      float4 bb0 = *(const float4*)(lnbg + fb + c);
      float4 bb1 = *(const float4*)(lnbg + fb + c + 4);
      bf16x8 ov;
      ov[0] = (bf16)((vals[i * 8 + 0] - mean) * rs * g0.x + bb0.x);
      ov[1] = (bf16)((vals[i * 8 + 1] - mean) * rs * g0.y + bb0.y);
      ov[2] = (bf16)((vals[i * 8 + 2] - mean) * rs * g0.z + bb0.z);
      ov[3] = (bf16)((vals[i * 8 + 3] - mean) * rs * g0.w + bb0.w);
      ov[4] = (bf16)((vals[i * 8 + 4] - mean) * rs * g1.x + bb1.x);
      ov[5] = (bf16)((vals[i * 8 + 5] - mean) * rs * g1.y + bb1.y);
      ov[6] = (bf16)((vals[i * 8 + 6] - mean) * rs * g1.z + bb1.z);
      ov[7] = (bf16)((vals[i * 8 + 7] - mean) * rs * g1.w + bb1.w);
      *(bf16x8*)(dst + i * 8) = ov;
    }
  }
}

// ---------------------------------------------------------------------------
// sel reduce: feats[m][h] (+=) sum_f v[f][m][h]*sw[m][f] (+pos_enc at end)
// ---------------------------------------------------------------------------
__global__ void __launch_bounds__(256, 4)
selreduce_kernel(const bf16* __restrict__ vbuf, const float* __restrict__ sw,
                 const float* __restrict__ pos, float* __restrict__ feats,
                 int f0, int FC, int flags)
{
  const int tid = threadIdx.x;
  const int m = blockIdx.x * 4 + (tid >> 6);
  const int hh = (tid & 63) * 4;
  float a0, a1, a2, a3;
  if (flags & 1) { a0 = a1 = a2 = a3 = 0.f; }
  else {
    float4 v = *(const float4*)(feats + (size_t)m * 256 + hh);
    a0 = v.x; a1 = v.y; a2 = v.z; a3 = v.w;
  }
  for (int fi = 0; fi < FC; ++fi) {
    float wgt = sw[(size_t)m * 128 + f0 + fi];
    bf16x4 v = *(const bf16x4*)(vbuf + ((size_t)fi * 1024 + m) * 256 + hh);
    a0 += wgt * (float)v[0]; a1 += wgt * (float)v[1];
    a2 += wgt * (float)v[2]; a3 += wgt * (float)v[3];
  }
  if (flags & 2) {
    float4 p = *(const float4*)(pos + (size_t)(m & 127) * 256 + hh);
    a0 += p.x; a1 += p.y; a2 += p.z; a3 += p.w;
  }
  float4 o; o.x = a0; o.y = a1; o.z = a2; o.w = a3;
  *(float4*)(feats + (size_t)m * 256 + hh) = o;
}

// ---------------------------------------------------------------------------
// LSTM v3 (proven, deterministic, 573us): unchanged.
// ---------------------------------------------------------------------------
__global__ void __launch_bounds__(256, 1)
lstm_mfma(const bf16* __restrict__ wl, const float* __restrict__ xpre0,
          const float* __restrict__ b0a, const float* __restrict__ b0b,
          const float* __restrict__ b1a, const float* __restrict__ b1b,
          bf16* __restrict__ h0seq, bf16* __restrict__ h1seq,
          float* __restrict__ aseq, unsigned* __restrict__ ctr)
{
  __shared__ float gbuf[4][16][8];
  const int tid = threadIdx.x;
  const int l = tid & 63, w = tid >> 6;
  const int layer = blockIdx.x >> 4, U = (blockIdx.x & 15) * 16;
  const int row = w * 256 + U + (l & 15);
  const int ko = (l >> 4) * 8;
  const bf16* whh = wl + (size_t)(layer ? 3 : 1) * 262144 + (size_t)row * 256;
  const bf16* wih1 = wl + (size_t)2 * 262144 + (size_t)row * 256;
  bf16x8 bw[8], bx[8];
  #pragma unroll
  for (int kt = 0; kt < 8; ++kt) bw[kt] = *(const bf16x8*)(whh + kt * 32 + ko);
  if (layer) {
    #pragma unroll
    for (int kt = 0; kt < 8; ++kt) bx[kt] = *(const bf16x8*)(wih1 + kt * 32 + ko);
  }
  const float bsum = layer ? (b1a[row] + b1b[row]) : (b0a[row] + b0b[row]);
  bf16* hs = layer ? h1seq : h0seq;
  unsigned* c0 = ctr;
  unsigned* c1 = ctr + 128;
  unsigned* cs = layer ? c1 : c0;
  float cstate = 0.f;
  const int au = tid >> 3, ab = tid & 7;

  for (int t = 0; t < 128; ++t) {
    float xp[4] = {0.f, 0.f, 0.f, 0.f};
    if (!layer && (l >> 4) < 2) {
      #pragma unroll
      for (int r = 0; r < 4; ++r) {
        int bb = (l >> 4) * 4 + r;
        xp[r] = xpre0[((size_t)((bb << 7) | t)) * 1024 + row];
      }
    }
    if (tid == 0) {
      if (layer == 0) {
        if (t > 0)
          while (__hip_atomic_load(c0 + t - 1, __ATOMIC_ACQUIRE, __HIP_MEMORY_SCOPE_AGENT) < 16u)
            __builtin_amdgcn_s_sleep(2);
      } else {
        while (__hip_atomic_load(c0 + t, __ATOMIC_ACQUIRE, __HIP_MEMORY_SCOPE_AGENT) < 16u)
          __builtin_amdgcn_s_sleep(2);
        if (t > 0)
          while (__hip_atomic_load(c1 + t - 1, __ATOMIC_ACQUIRE, __HIP_MEMORY_SCOPE_AGENT) < 16u)
            __builtin_amdgcn_s_sleep(2);
      }
    }
    __syncthreads();
    floatx4 acc; acc[0] = acc[1] = acc[2] = acc[3] = 0.f;
    if (t > 0) {
      const bf16* hp = hs + (size_t)(t - 1) * 4096 + (size_t)(l & 15) * 256 + ko;
      #pragma unroll
      for (int kt = 0; kt < 8; ++kt)
        acc = MFMA16(*(const bf16x8*)(hp + kt * 32), bw[kt], acc);
    }
    if (layer) {
      const bf16* hp = h0seq + (size_t)t * 4096 + (size_t)(l & 15) * 256 + ko;
      #pragma unroll
      for (int kt = 0; kt < 8; ++kt)
        acc = MFMA16(*(const bf16x8*)(hp + kt * 32), bx[kt], acc);
    }
    if ((l >> 4) < 2) {
      #pragma unroll
      for (int r = 0; r < 4; ++r) {
        int bb = (l >> 4) * 4 + r;
        gbuf[w][l & 15][bb] = acc[r] + bsum + xp[r];
      }
    }
    __syncthreads();
    if (tid < 128) {
      float gi = gbuf[0][au][ab], gf = gbuf[1][au][ab];
      float gg = gbuf[2][au][ab], go = gbuf[3][au][ab];
      cstate = sigmf_(gf) * cstate + sigmf_(gi) * tanhf(gg);
      float h = sigmf_(go) * tanhf(cstate);
      hs[(size_t)t * 4096 + (size_t)ab * 256 + U + au] = (bf16)h;
      if (layer) aseq[((size_t)((ab << 7) | t)) * 256 + U + au] = h;
    }
    __syncthreads();
    if (tid == 0) {
      __threadfence();
      __hip_atomic_fetch_add(cs + t, 1u, __ATOMIC_RELEASE, __HIP_MEMORY_SCOPE_AGENT);
    }
  }
}

// ---------------------------------------------------------------------------
// Fused QKV + attention per (b,h): A-tile of a[b] in LDS (bf16 swizzled),
// QKV via MFMA (weights from global qkvT, L2-hot), fp32 QKV in LDS, then
// the proven VALU softmax/ctx core. Dynamic LDS 126976 B.
// ---------------------------------------------------------------------------
__global__ void __launch_bounds__(256, 1)
attn_qkv(const float* __restrict__ a, const bf16* __restrict__ qkvT,
         float* __restrict__ ctxo)
{
  extern __shared__ char sm[];
  float* Qb = (float*)(sm + 65536);     // [128][40] fp32
  float* Kb = (float*)(sm + 86016);
  float* Vb = (float*)(sm + 106496);
  const int tid = threadIdx.x;
  const int b = blockIdx.x >> 3, h = blockIdx.x & 7;
  const int l = tid & 63, w = tid >> 6;
  // stage a[b] -> bf16 swizzled [128][256]
  {
    int m = tid >> 1, ch = (tid & 1) * 128;
    const float* src = a + (size_t)(b * 128 + m) * 256 + ch;
    #pragma unroll
    for (int cc = 0; cc < 16; ++cc) {
      float4 v0 = *(const float4*)(src + cc * 8);
      float4 v1 = *(const float4*)(src + cc * 8 + 4);
      bf16x8 hv;
      hv[0]=(bf16)v0.x; hv[1]=(bf16)v0.y; hv[2]=(bf16)v0.z; hv[3]=(bf16)v0.w;
      hv[4]=(bf16)v1.x; hv[5]=(bf16)v1.y; hv[6]=(bf16)v1.z; hv[7]=(bf16)v1.w;
      int k = ch + cc * 8;
      unsigned off = ((unsigned)(m * 512 + k * 2)) ^ ((unsigned)(m & 7) << 4);
      *(bf16x8*)(sm + off) = hv;
    }
  }
  __syncthreads();
  // QKV MFMA: wave w -> rows 32w..32w+31; j: 0,1=Q 2,3=K 4,5=V
  const int row = l & 15, kb = (l >> 4) * 8;
  floatx4 acc[2][6];
  #pragma unroll
  for (int i = 0; i < 2; ++i)
    #pragma unroll
    for (int j = 0; j < 6; ++j)
      #pragma unroll
      for (int r = 0; r < 4; ++r) acc[i][j][r] = 0.f;
  for (int k0 = 0; k0 < 256; k0 += 32) {
    int kloc = k0 + kb;
    bf16x8 af[2];
    #pragma unroll
    for (int i = 0; i < 2; ++i) {
      int m = 32 * w + 16 * i + row;
      unsigned off = ((unsigned)(m * 512 + kloc * 2)) ^ ((unsigned)(m & 7) << 4);
      af[i] = *(const bf16x8*)(sm + off);
    }
    #pragma unroll
    for (int j = 0; j < 6; ++j) {
      int nn = h * 32 + (j & 1) * 16 + row;
      const bf16* bp = qkvT + (size_t)(j >> 1) * 65536 + (size_t)nn * 256 + kloc;
      bf16x8 bf_ = *(const bf16x8*)bp;
      #pragma unroll
      for (int i = 0; i < 2; ++i)
        acc[i][j] = MFMA16(af[i], bf_, acc[i][j]);
    }
  }
  // write QKV fp32 to LDS
  #pragma unroll
  for (int i = 0; i < 2; ++i)
    #pragma unroll
    for (int j = 0; j < 6; ++j) {
      float* dst = (j >> 1) == 0 ? Qb : ((j >> 1) == 1 ? Kb : Vb);
      #pragma unroll
      for (int r = 0; r < 4; ++r) {
        int m = 32 * w + 16 * i + ((l >> 4) << 2) + r;
        int nn = (j & 1) * 16 + (l & 15);
        dst[m * 40 + nn] = acc[i][j][r];
      }
    }
  __syncthreads();
  // proven VALU attention core (fp32)
  const int s = tid >> 1, half = tid & 1;
  float q[32];
  #pragma unroll
  for (int i = 0; i < 32; ++i) q[i] = Qb[s * 40 + i];
  const float scale = 0.17677669529663687f;
  float se = 0.f;
  float ca[32];
  #pragma unroll
  for (int i = 0; i < 32; ++i) ca[i] = 0.f;
  for (int c0 = 0; c0 < 64; ++c0) {
    int c = half * 64 + c0;
    float d = 0.f;
    #pragma unroll
    for (int i = 0; i < 32; ++i) d += q[i] * Kb[c * 40 + i];
    float e = expf(d * scale);
    se += e;
    #pragma unroll
    for (int i = 0; i < 32; ++i) ca[i] += e * Vb[c * 40 + i];
  }
  se += __shfl_xor(se, 1, 64);
  #pragma unroll
  for (int i = 0; i < 32; ++i) ca[i] += __shfl_xor(ca[i], 1, 64);
  if (half == 0) {
    float inv = 1.f / se;
    float* outp = ctxo + ((size_t)(b * 128 + s)) * 256 + h * 32;
    #pragma unroll
    for (int i = 0; i < 32; i += 4) {
      float4 v; v.x = ca[i] * inv; v.y = ca[i + 1] * inv; v.z = ca[i + 2] * inv; v.w = ca[i + 3] * inv;
      *(float4*)(outp + i) = v;
    }
  }
}

// ---------------------------------------------------------------------------
// Fused out-proj + bias + residual + LN. Grid 8 (128-row tiles), 256 thr.
// Tile 128x256, K=256. LDS: A [128][64] bf16 @0, B [256][64] bf16 @16384.
// ---------------------------------------------------------------------------
__global__ void __launch_bounds__(256, 1)
proj_ln(const float* __restrict__ A, const bf16* __restrict__ BT,
        const float* __restrict__ bias, const float* __restrict__ resid,
        const float* __restrict__ g, const float* __restrict__ bta,
        float* __restrict__ out, float* __restrict__ mirror)
{
  __shared__ char sm[16384 + 32768];
  const int tid = threadIdx.x;
  const int bm = blockIdx.x * 128;
  const int l = tid & 63, w = tid >> 6;
  const int row = l & 15, kb = (l >> 4) * 8;
  floatx4 acc[2][16];
  #pragma unroll
  for (int i = 0; i < 2; ++i)
    #pragma unroll
    for (int j = 0; j < 16; ++j)
      #pragma unroll
      for (int r = 0; r < 4; ++r) acc[i][j][r] = 0.f;

  for (int k0 = 0; k0 < 256; k0 += 64) {
    {
      int r0 = tid >> 4, kq = (tid & 15) * 4;
      #pragma unroll
      for (int p = 0; p < 8; ++p) {
        int m = r0 + p * 16;
        float4 v = *(const float4*)(A + (size_t)(bm + m) * 256 + k0 + kq);
        bf16x4 hv; hv[0]=(bf16)v.x; hv[1]=(bf16)v.y; hv[2]=(bf16)v.z; hv[3]=(bf16)v.w;
        unsigned off = ((unsigned)(m * 128 + kq * 2)) ^ ((unsigned)(m & 7) << 4);
        *(bf16x4*)(sm + off) = hv;
      }
      // B stage: thread = row n (0..255), 64 k as 8x bf16x8
      int n = tid;
      const bf16* src = BT + (size_t)n * 256 + k0;
      #pragma unroll
      for (int qq = 0; qq < 8; ++qq) {
        unsigned ro = 16384u + (((unsigned)(n * 128 + qq * 16)) ^ ((unsigned)(n & 7) << 4));
        *(bf16x8*)(sm + ro) = *(const bf16x8*)(src + qq * 8);
      }
    }
    __syncthreads();
    #pragma unroll
    for (int kk = 0; kk < 64; kk += 32) {
      int kloc = kk + kb;
      bf16x8 af[2];
      #pragma unroll
      for (int i = 0; i < 2; ++i) {
        int m = 32 * w + 16 * i + row;
        unsigned off = ((unsigned)(m * 128 + kloc * 2)) ^ ((unsigned)(m & 7) << 4);
        af[i] = *(const bf16x8*)(sm + off);
      }
      #pragma unroll
      for (int j = 0; j < 16; ++j) {
        int n = 16 * j + row;
        unsigned off = 16384u + (((unsigned)(n * 128 + kloc * 2)) ^ ((unsigned)(n & 7) << 4));
        bf16x8 bf_ = *(const bf16x8*)(sm + off);
        #pragma unroll
        for (int i = 0; i < 2; ++i)
          acc[i][j] = MFMA16(af[i], bf_, acc[i][j]);
      }
    }
    __syncthreads();
  }
  // epilogue: bias + resid, LN per row (16-lane shfl reduce), write
  #pragma unroll
  for (int i = 0; i < 2; ++i)
    #pragma unroll
    for (int r = 0; r < 4; ++r) {
      int grow = bm + 32 * w + 16 * i + ((l >> 4) << 2) + r;
      float vv[16];
      float s = 0.f, s2 = 0.f;
      #pragma unroll
      for (int j = 0; j < 16; ++j) {
        int gcol = 16 * j + (l & 15);
        float v = acc[i][j][r] + bias[gcol] + resid[(size_t)grow * 256 + gcol];
        vv[j] = v; s += v; s2 += v * v;
      }
      s += __shfl_xor(s, 1, 64);  s += __shfl_xor(s, 2, 64);
      s += __shfl_xor(s, 4, 64);  s += __shfl_xor(s, 8, 64);
      s2 += __shfl_xor(s2, 1, 64); s2 += __shfl_xor(s2, 2, 64);
      s2 += __shfl_xor(s2, 4, 64); s2 += __shfl_xor(s2, 8, 64);
      float mean = s * (1.f / 256.f);
      float var = s2 * (1.f / 256.f) - mean * mean;
      float rs = rsqrtf(var + 1e-5f);
      #pragma unroll
      for (int j = 0; j < 16; ++j) {
        int gcol = 16 * j + (l & 15);
        float o = (vv[j] - mean) * rs * g[gcol] + bta[gcol];
        out[(size_t)grow * 256 + gcol] = o;
        if (mirror) mirror[(size_t)grow * 256 + gcol] = o;
      }
    }
}

__global__ void __launch_bounds__(256)
gctx_kernel(const float* __restrict__ a, float* __restrict__ g)
{
  int b = blockIdx.x, hh = threadIdx.x;
  float s = 0.f;
  for (int ss = 0; ss < 128; ++ss) s += a[((size_t)b * 128 + ss) * 256 + hh];
  g[b * 256 + hh] = s * (1.f / 128.f);
}

__global__ void __launch_bounds__(256, 1)
head_kernel(const float* __restrict__ g, const float* __restrict__ w1,
            const float* __restrict__ b1, const float* __restrict__ w2,
            const float* __restrict__ b2, const float* __restrict__ qw,
            const float* __restrict__ qb, float* __restrict__ dout)
{
  __shared__ float hid[8][128];
  const int tid = threadIdx.x;
  for (int o = tid; o < 1024; o += 256) {
    int b = o >> 7, j = o & 127;
    float s = b1[j];
    for (int k = 0; k < 256; ++k) s += g[b * 256 + k] * w1[(size_t)k * 128 + j];
    hid[b][j] = s > 0.f ? s : 0.f;
  }
  __syncthreads();
  if (tid < 192) {
    int b = tid / 24, j = tid - b * 24;
    float s = b2[j];
    for (int k = 0; k < 128; ++k) s += hid[b][k] * w2[(size_t)k * 24 + j];
    dout[b * 24 + j] = s;
  }
  for (int o = tid; o < 576; o += 256) {
    int qi = o / 192, rr = o - qi * 192, b = rr / 24, j = rr - b * 24;
    float s = qb[qi * 24 + j];
    for (int k = 0; k < 256; ++k) s += g[b * 256 + k] * qw[((size_t)qi * 256 + k) * 24 + j];
    dout[192 + o] = s;
  }
}

// ---------------------------------------------------------------------------
extern "C" void kernel_launch(void* const* d_in, const int* in_sizes, int n_in,
                              void* d_out, int out_size, void* d_ws, size_t ws_size,
                              hipStream_t stream)
{
  (void)in_sizes; (void)n_in; (void)out_size;
  auto F = [&](int i) { return (const float*)d_in[i]; };
  char* ws = (char*)d_ws;
  size_t o = 0;
  auto alloc = [&](size_t b) { size_t r = o; o = (o + b + 255) & ~(size_t)255; return r; };

  size_t svT_o  = alloc((size_t)3 * 128 * 65536 * 2);
  size_t wl_o   = alloc((size_t)4 * 262144 * 2);
  size_t qkvT_o = alloc((size_t)4 * 196608 * 2);
  size_t woT_o  = alloc((size_t)4 * 65536 * 2);
  size_t w1T_o  = alloc(256 * 128 * 2);
  size_t w2T_o  = alloc(256 * 256 * 2);
  size_t goT_o  = alloc(256 * 256 * 2);
  size_t swT_o  = alloc(128 * 128 * 2);
  size_t xT_o   = alloc(128 * 1024 * 2);
  size_t h_o    = alloc((size_t)1024 * 256 * 4);
  size_t h2_o   = alloc((size_t)1024 * 256 * 4);
  size_t go_o   = alloc((size_t)1024 * 256 * 4);
  size_t skip_o = alloc((size_t)1024 * 128 * 4);
  size_t feat_o = alloc((size_t)1024 * 256 * 4);
  size_t xpre_o = alloc((size_t)1024 * 1024 * 4);
  size_t ctx_o  = alloc((size_t)1024 * 256 * 4);
  size_t aA_o   = alloc((size_t)1024 * 256 * 4);
  size_t aB_o   = alloc((size_t)1024 * 256 * 4);
  size_t gctx_o = alloc(8 * 256 * 4);
  size_t z_o    = alloc((size_t)2 * 1048576 + 1024);
  size_t aseq_o = alloc((size_t)1024 * 256 * 4);
  int FC = 128;
  while (FC > 4 && o + (size_t)FC * 1024 * 256 * 2 > ws_size) FC >>= 1;
  size_t vb_o = alloc((size_t)FC * 1024 * 256 * 2);
  if (o > ws_size) return;

  bf16* svTp  = (bf16*)(ws + svT_o);
  bf16* wlp   = (bf16*)(ws + wl_o);
  bf16* qkvTp = (bf16*)(ws + qkvT_o);
  bf16* woTp  = (bf16*)(ws + woT_o);
  bf16* w1Tp  = (bf16*)(ws + w1T_o);
  bf16* w2Tp  = (bf16*)(ws + w2T_o);
  bf16* goTp  = (bf16*)(ws + goT_o);
  bf16* swTp  = (bf16*)(ws + swT_o);
  bf16* xTp   = (bf16*)(ws + xT_o);
  float* hp    = (float*)(ws + h_o);
  float* h2p   = (float*)(ws + h2_o);
  float* gop   = (float*)(ws + go_o);
  float* skipp = (float*)(ws + skip_o);
  float* featp = (float*)(ws + feat_o);
  float* xprep = (float*)(ws + xpre_o);
  float* ctxp  = (float*)(ws + ctx_o);
  float* aAp   = (float*)(ws + aA_o);
  float* aBp   = (float*)(ws + aB_o);
  float* gctxp = (float*)(ws + gctx_o);
  bf16* h0p    = (bf16*)(ws + z_o);
  bf16* h1p    = (bf16*)(ws + z_o + 1048576);
  unsigned* ctrp = (unsigned*)(ws + z_o + 2097152);
  float* aseqp = (float*)(ws + aseq_o);
  bf16* vbp    = (bf16*)(ws + vb_o);

  // d_out FP32: pf@0[192], q10@192, q50@384, q90@576, sw@768[131072], a@131840[262144]
  float* outp  = (float*)d_out;
  float* sw_do = outp + 768;
  float* a_do  = outp + 131840;

  hipMemsetAsync(ws + z_o, 0, 2097152 + 1024, stream);
  hipFuncSetAttribute((const void*)attn_qkv,
                      hipFuncAttributeMaxDynamicSharedMemorySize, 126976);

  // ---- weight prep ----
  transpose_sv<<<dim3(16, 384), 256, 0, stream>>>(F(15), F(17), F(19), svTp);
  {
    TJobs tj; int nj = 0;
    auto addj = [&](const float* s, bf16* d, int R, int C) { tj.j[nj].src = s; tj.j[nj].dst = d; tj.j[nj].R = R; tj.j[nj].C = C; ++nj; };
    for (int l = 0; l < 4; ++l) {
      addj(F(34) + (size_t)l * 65536, qkvTp + (size_t)l * 196608, 256, 256);
      addj(F(35) + (size_t)l * 65536, qkvTp + (size_t)l * 196608 + 65536, 256, 256);
      addj(F(36) + (size_t)l * 65536, qkvTp + (size_t)l * 196608 + 131072, 256, 256);
      addj(F(37) + (size_t)l * 65536, woTp + (size_t)l * 65536, 256, 256);
    }
    addj(F(1), w1Tp, 128, 256);
    addj(F(3), w2Tp, 256, 256);
    addj(F(7), goTp, 256, 128);
    addj(F(5), goTp + 128 * 256, 256, 128);
    addj(F(9), swTp, 128, 128);
    addj(F(0), xTp, 1024, 128);
    transpose_misc<<<dim3(32, 22), 256, 0, stream>>>(tj);
  }
  cvt4_kernel<<<1024, 256, 0, stream>>>(F(26), F(27), F(30), F(31), wlp);

  auto gemm = [&](int epi, const float* A, int lda, const bf16* BT, int ldb,
                  float* C, int ldc, int M, int N, int K,
                  const float* b1, const float* b2r) {
    dim3 g(N / 64, M / 128);
    switch (epi) {
      case 0: gemm_bf16<0><<<g, 256, 0, stream>>>(A, lda, BT, ldb, C, ldc, b1, b2r, K); break;
      case 1: gemm_bf16<1><<<g, 256, 0, stream>>>(A, lda, BT, ldb, C, ldc, b1, b2r, K); break;
      case 2: gemm_bf16<2><<<g, 256, 0, stream>>>(A, lda, BT, ldb, C, ldc, b1, b2r, K); break;
      case 3: gemm_bf16<3><<<g, 256, 0, stream>>>(A, lda, BT, ldb, C, ldc, b1, b2r, K); break;
      case 4: gemm_bf16<4><<<g, 256, 0, stream>>>(A, lda, BT, ldb, C, ldc, b1, b2r, K); break;
    }
  };

  // ---- flattened GRN -> variable selection weights ----
  gemm(2, F(0), 128, w1Tp, 128, hp, 256, 1024, 256, 128, F(2), nullptr);
  gemm(2, hp, 256, w2Tp, 256, h2p, 256, 1024, 256, 256, F(4), nullptr);
  gemm(3, h2p, 256, goTp, 256, gop, 256, 1024, 256, 256, F(8), F(6));
  gemm(1, F(0), 128, swTp, 128, skipp, 128, 1024, 128, 128, F(10), nullptr);
  grnflat_sw_kernel<<<256, 256, 0, stream>>>(gop, skipp, F(11), F(12), sw_do);

  // ---- per-variable GRNs ----
  int chunks = 128 / FC;
  for (int c = 0; c < chunks; ++c) {
    pervar_kernel<<<dim3(16, FC), 512, 0, stream>>>(
        xTp, svTp, F(13), F(14), F(16), F(18), F(20), F(21), F(22), F(23), F(24),
        vbp, c * FC);
    selreduce_kernel<<<256, 256, 0, stream>>>(
        vbp, sw_do, F(25), featp, c * FC, FC,
        (c == 0 ? 1 : 0) | (c == chunks - 1 ? 2 : 0));
  }

  // ---- LSTM ----
  gemm(0, featp, 256, wlp, 256, xprep, 1024, 1024, 1024, 256, nullptr, nullptr);
  lstm_mfma<<<32, 256, 0, stream>>>(wlp, xprep, F(28), F(29), F(32), F(33),
                                    h0p, h1p, aseqp, ctrp);

  // ---- attention layers (fused: attn_qkv + proj_ln) ----
  const float* ain = aseqp;
  float* louts[4] = {aAp, aBp, aAp, aBp};
  for (int l = 0; l < 4; ++l) {
    attn_qkv<<<64, 256, 126976, stream>>>(ain, qkvTp + (size_t)l * 196608, ctxp);
    proj_ln<<<8, 256, 0, stream>>>(ctxp, woTp + (size_t)l * 65536,
                                   F(38) + (size_t)l * 256, ain,
                                   F(39) + (size_t)l * 256, F(40) + (size_t)l * 256,
                                   louts[l], l == 3 ? a_do : (float*)nullptr);
    ain = louts[l];
  }

  // ---- heads ----
  gctx_kernel<<<8, 256, 0, stream>>>(aBp, gctxp);
  head_kernel<<<1, 256, 0, stream>>>(gctxp, F(41), F(42), F(43), F(44), F(45), F(46), outp);
}

// Round 13
// 1110.897 us; speedup vs baseline: 1.1696x; 1.1696x over previous
//
#include <hip/hip_runtime.h>
#include <cstdint>
#include <cstddef>

typedef __bf16 bf16;
typedef __attribute__((ext_vector_type(4))) __bf16 bf16x4;
typedef __attribute__((ext_vector_type(8))) __bf16 bf16x8;
typedef __attribute__((ext_vector_type(4))) float floatx4;

#define MFMA16(a,b,c) __builtin_amdgcn_mfma_f32_16x16x32_bf16(a,b,c,0,0,0)

__device__ __forceinline__ float sigmf_(float x){ return 1.f/(1.f+expf(-x)); }
__device__ __forceinline__ float eluf_(float x){ return x>0.f ? x : (expf(x)-1.f); }

// ---------------------------------------------------------------------------
// MFMA GEMM: C[M,N] = epi(A[M,K] @ B^T[N,K]) ; A fp32 (cvt->bf16), BT bf16.
// Block 256 thr, tile 128x64, BK=64, swizzled LDS (byte ^= (row&7)<<4).
// EPI: 0 none, 1 +bias, 2 elu(+bias), 3 +bias2(split@128), 4 +bias+resid
// ---------------------------------------------------------------------------
template<int EPI>
__global__ void __launch_bounds__(256, 2)
gemm_bf16(const float* __restrict__ A, int lda,
          const bf16* __restrict__ BT, int ldb,
          float* __restrict__ C, int ldc,
          const float* __restrict__ b1, const float* __restrict__ b2r,
          int K)
{
  __shared__ char sm[16384 + 8192];
  const int tid = threadIdx.x;
  const int bm = blockIdx.y * 128, bn = blockIdx.x * 64;
  const int l = tid & 63, w = tid >> 6;
  const int wm = (w >> 1) * 64, wn = (w & 1) * 32;
  floatx4 acc[4][2];
  #pragma unroll
  for (int i = 0; i < 4; ++i)
    #pragma unroll
    for (int j = 0; j < 2; ++j)
      #pragma unroll
      for (int r = 0; r < 4; ++r) acc[i][j][r] = 0.f;

  for (int k0 = 0; k0 < K; k0 += 64) {
    {
      int r0 = tid >> 4, kq = (tid & 15) * 4;
      #pragma unroll
      for (int p = 0; p < 8; ++p) {
        int m = r0 + p * 16;
        float4 v = *(const float4*)(A + (size_t)(bm + m) * lda + k0 + kq);
        bf16x4 hv; hv[0]=(bf16)v.x; hv[1]=(bf16)v.y; hv[2]=(bf16)v.z; hv[3]=(bf16)v.w;
        unsigned off = ((unsigned)(m * 128 + kq * 2)) ^ ((unsigned)(m & 7) << 4);
        *(bf16x4*)(sm + off) = hv;
      }
      int n = tid >> 2, c = (tid & 3) * 16;
      const bf16* src = BT + (size_t)(bn + n) * ldb + k0 + c;
      bf16x8 v0 = *(const bf16x8*)(src);
      bf16x8 v1 = *(const bf16x8*)(src + 8);
      unsigned o0 = 16384u + (((unsigned)(n * 128 + c * 2))      ^ ((unsigned)(n & 7) << 4));
      unsigned o1 = 16384u + (((unsigned)(n * 128 + c * 2 + 16)) ^ ((unsigned)(n & 7) << 4));
      *(bf16x8*)(sm + o0) = v0;
      *(bf16x8*)(sm + o1) = v1;
    }
    __syncthreads();
    const int row = l & 15, kb = (l >> 4) * 8;
    #pragma unroll
    for (int kk = 0; kk < 64; kk += 32) {
      bf16x8 a[4], b[2];
      #pragma unroll
      for (int i = 0; i < 4; ++i) {
        int m = wm + i * 16 + row;
        unsigned off = ((unsigned)(m * 128 + (kk + kb) * 2)) ^ ((unsigned)(m & 7) << 4);
        a[i] = *(const bf16x8*)(sm + off);
      }
      #pragma unroll
      for (int j = 0; j < 2; ++j) {
        int n = wn + j * 16 + row;
        unsigned off = 16384u + (((unsigned)(n * 128 + (kk + kb) * 2)) ^ ((unsigned)(n & 7) << 4));
        b[j] = *(const bf16x8*)(sm + off);
      }
      #pragma unroll
      for (int i = 0; i < 4; ++i)
        #pragma unroll
        for (int j = 0; j < 2; ++j)
          acc[i][j] = MFMA16(a[i], b[j], acc[i][j]);
    }
    __syncthreads();
  }
  #pragma unroll
  for (int i = 0; i < 4; ++i)
    #pragma unroll
    for (int j = 0; j < 2; ++j)
      #pragma unroll
      for (int r = 0; r < 4; ++r) {
        int grow = bm + wm + i * 16 + ((l >> 4) << 2) + r;
        int gcol = bn + wn + j * 16 + (l & 15);
        float v = acc[i][j][r];
        if (EPI == 1) v += b1[gcol];
        else if (EPI == 2) { v += b1[gcol]; v = eluf_(v); }
        else if (EPI == 3) { v += (gcol < 128) ? b1[gcol] : b2r[gcol - 128]; }
        else if (EPI == 4) { v += b1[gcol] + b2r[(size_t)grow * ldc + gcol]; }
        C[(size_t)grow * ldc + gcol] = v;
      }
}

// ---------------------------------------------------------------------------
// 64x64 transpose+cvt tile helper (fp32 src -> bf16 dst, dst = src^T)
// ---------------------------------------------------------------------------
__device__ __forceinline__ void tile_tr64(const float* __restrict__ src, int srcld,
                                          bf16* __restrict__ dst, int dstld,
                                          float (*ld)[72])
{
  const int tid = threadIdx.x;
  const int r = tid >> 2, q = tid & 3;
  #pragma unroll
  for (int i = 0; i < 4; ++i) {
    int col = q * 16 + i * 4;
    *(float4*)&ld[r][col] = *(const float4*)(src + (size_t)r * srcld + col);
  }
  __syncthreads();
  bf16x8 o0, o1;
  #pragma unroll
  for (int i = 0; i < 8; ++i) o0[i] = (bf16)ld[q * 16 + i][r];
  #pragma unroll
  for (int i = 0; i < 8; ++i) o1[i] = (bf16)ld[q * 16 + 8 + i][r];
  *(bf16x8*)(dst + (size_t)r * dstld + q * 16) = o0;
  *(bf16x8*)(dst + (size_t)r * dstld + q * 16 + 8) = o1;
}

__global__ void __launch_bounds__(256)
transpose_sv(const float* __restrict__ w2, const float* __restrict__ wo,
             const float* __restrict__ wg, bf16* __restrict__ svT)
{
  __shared__ float ld[64][72];
  int mat = blockIdx.y >> 7;
  int f = blockIdx.y & 127;
  const float* src = (mat == 0 ? w2 : (mat == 1 ? wo : wg)) + (size_t)f * 65536;
  bf16* dst = svT + (size_t)blockIdx.y * 65536;
  int tc = blockIdx.x & 3, tr = blockIdx.x >> 2;
  tile_tr64(src + (size_t)(tr * 64) * 256 + tc * 64, 256,
            dst + (size_t)(tc * 64) * 256 + tr * 64, 256, ld);
}

struct TJob { const float* src; bf16* dst; int R; int C; };
struct TJobs { TJob j[22]; };

__global__ void __launch_bounds__(256)
transpose_misc(TJobs jobs)
{
  __shared__ float ld[64][72];
  TJob J = jobs.j[blockIdx.y];
  int ntc = J.C >> 6;
  int tiles = (J.R >> 6) * ntc;
  if ((int)blockIdx.x >= tiles) return;
  int tc = blockIdx.x % ntc, tr = blockIdx.x / ntc;
  tile_tr64(J.src + (size_t)(tr * 64) * J.C + tc * 64, J.C,
            J.dst + (size_t)(tc * 64) * J.R + tr * 64, J.R, ld);
}

// fp32 -> bf16 convert of 4 lstm weight matrices (each 262144 elems)
__global__ void __launch_bounds__(256)
cvt4_kernel(const float* __restrict__ s0, const float* __restrict__ s1,
            const float* __restrict__ s2, const float* __restrict__ s3,
            bf16* __restrict__ dst)
{
  size_t i = ((size_t)blockIdx.x * 256 + threadIdx.x) * 4;
  int mat = (int)(i >> 18);
  const float* s = (mat == 0) ? s0 : (mat == 1) ? s1 : (mat == 2) ? s2 : s3;
  float4 v = *(const float4*)(s + (i & 262143));
  bf16x4 o; o[0]=(bf16)v.x; o[1]=(bf16)v.y; o[2]=(bf16)v.z; o[3]=(bf16)v.w;
  *(bf16x4*)(dst + i) = o;
}

// ---------------------------------------------------------------------------
// GRN-flat combine: pre = sigmoid(g)*o + skip ; LN(128) ; softmax(128)
// ---------------------------------------------------------------------------
__global__ void __launch_bounds__(256, 4)
grnflat_sw_kernel(const float* __restrict__ go, const float* __restrict__ skip,
                  const float* __restrict__ lng, const float* __restrict__ lnb,
                  float* __restrict__ sw_out)
{
  const int tid = threadIdx.x;
  const int m = blockIdx.x * 4 + (tid >> 6);
  const int l = tid & 63, c = l * 2;
  float g0 = go[(size_t)m * 256 + c],       g1 = go[(size_t)m * 256 + c + 1];
  float o0 = go[(size_t)m * 256 + 128 + c], o1 = go[(size_t)m * 256 + 128 + c + 1];
  float sk0 = skip[(size_t)m * 128 + c],    sk1 = skip[(size_t)m * 128 + c + 1];
  float p0 = sigmf_(g0) * o0 + sk0;
  float p1 = sigmf_(g1) * o1 + sk1;
  float s = p0 + p1, s2 = p0 * p0 + p1 * p1;
  #pragma unroll
  for (int k = 1; k < 64; k <<= 1) { s += __shfl_xor(s, k, 64); s2 += __shfl_xor(s2, k, 64); }
  float mean = s * (1.f / 128.f);
  float var = s2 * (1.f / 128.f) - mean * mean;
  float rs = rsqrtf(var + 1e-5f);
  float t0 = (p0 - mean) * rs * lng[c] + lnb[c];
  float t1 = (p1 - mean) * rs * lng[c + 1] + lnb[c + 1];
  float mx = fmaxf(t0, t1);
  #pragma unroll
  for (int k = 1; k < 64; k <<= 1) mx = fmaxf(mx, __shfl_xor(mx, k, 64));
  float e0 = expf(t0 - mx), e1 = expf(t1 - mx);
  float se = e0 + e1;
  #pragma unroll
  for (int k = 1; k < 64; k <<= 1) se += __shfl_xor(se, k, 64);
  float inv = 1.f / se;
  float2 wv; wv.x = e0 * inv; wv.y = e1 * inv;
  *(float2*)(sw_out + (size_t)m * 128 + c) = wv;
}

// ---------------------------------------------------------------------------
// Per-variable GRN (MFMA): block = (feature f, 64-token tile). 512 thr, 8 waves.
// ---------------------------------------------------------------------------
__global__ void __launch_bounds__(512, 2)
pervar_kernel(const bf16* __restrict__ xT, const bf16* __restrict__ svT,
              const float* __restrict__ w1g, const float* __restrict__ b1g,
              const float* __restrict__ b2g, const float* __restrict__ bog,
              const float* __restrict__ bgg, const float* __restrict__ swg,
              const float* __restrict__ sbg, const float* __restrict__ lngg,
              const float* __restrict__ lnbg,
              bf16* __restrict__ vbuf, int f0)
{
  __shared__ char sm[65536];
  const int tid = threadIdx.x;
  const int fl = blockIdx.y, f = f0 + fl, tile = blockIdx.x;
  const int l = tid & 63, w = tid >> 6;
  const int wm = (w >> 2) * 32, wn = (w & 3) * 64;
  const int row = l & 15, kb = (l >> 4) * 8;
  const size_t fb = (size_t)f * 256;

  {
    int m = tid >> 3, ks8 = (tid & 7) * 32;
    float x = (float)xT[(size_t)f * 1024 + tile * 64 + m];
    #pragma unroll
    for (int i = 0; i < 4; ++i) {
      int k = ks8 + i * 8;
      float4 w0v = *(const float4*)(w1g + fb + k);
      float4 w1v = *(const float4*)(w1g + fb + k + 4);
      float4 b0v = *(const float4*)(b1g + fb + k);
      float4 b1v = *(const float4*)(b1g + fb + k + 4);
      bf16x8 hv;
      hv[0] = (bf16)eluf_(x * w0v.x + b0v.x);
      hv[1] = (bf16)eluf_(x * w0v.y + b0v.y);
      hv[2] = (bf16)eluf_(x * w0v.z + b0v.z);
      hv[3] = (bf16)eluf_(x * w0v.w + b0v.w);
      hv[4] = (bf16)eluf_(x * w1v.x + b1v.x);
      hv[5] = (bf16)eluf_(x * w1v.y + b1v.y);
      hv[6] = (bf16)eluf_(x * w1v.z + b1v.z);
      hv[7] = (bf16)eluf_(x * w1v.w + b1v.w);
      unsigned off = ((unsigned)(m * 512 + k * 2)) ^ ((unsigned)(m & 7) << 4);
      *(bf16x8*)(sm + off) = hv;
    }
  }

  auto stageB = [&](const bf16* BT, int ks) {
    int n = tid >> 1, c = (tid & 1) * 32;
    const bf16* src = BT + (size_t)n * 256 + ks * 64 + c;
    #pragma unroll
    for (int qq = 0; qq < 4; ++qq) {
      unsigned ro = (((unsigned)(n * 128 + (c + qq * 8) * 2)) ^ ((unsigned)(n & 7) << 4));
      *(bf16x8*)(sm + 32768 + ro) = *(const bf16x8*)(src + qq * 8);
    }
  };

  floatx4 acc1[2][4];
  #pragma unroll
  for (int i = 0; i < 2; ++i)
    #pragma unroll
    for (int j = 0; j < 4; ++j)
      #pragma unroll
      for (int r = 0; r < 4; ++r) acc1[i][j][r] = 0.f;
  const bf16* w2T = svT + (size_t)f * 65536;
  for (int ks = 0; ks < 4; ++ks) {
    __syncthreads();
    stageB(w2T, ks);
    __syncthreads();
    #pragma unroll
    for (int kk = 0; kk < 64; kk += 32) {
      int kloc = kk + kb;
      bf16x8 a[2], b[4];
      #pragma unroll
      for (int i = 0; i < 2; ++i) {
        int m = wm + i * 16 + row;
        unsigned off = ((unsigned)(m * 512 + (ks * 64 + kloc) * 2)) ^ ((unsigned)(m & 7) << 4);
        a[i] = *(const bf16x8*)(sm + off);
      }
      #pragma unroll
      for (int j = 0; j < 4; ++j) {
        int n = wn + j * 16 + row;
        unsigned off = 32768u + (((unsigned)(n * 128 + kloc * 2)) ^ ((unsigned)(n & 7) << 4));
        b[j] = *(const bf16x8*)(sm + off);
      }
      #pragma unroll
      for (int i = 0; i < 2; ++i)
        #pragma unroll
        for (int j = 0; j < 4; ++j)
          acc1[i][j] = MFMA16(a[i], b[j], acc1[i][j]);
    }
  }
  __syncthreads();
  #pragma unroll
  for (int i = 0; i < 2; ++i)
    #pragma unroll
    for (int j = 0; j < 4; ++j)
      #pragma unroll
      for (int r = 0; r < 4; ++r) {
        int m = wm + i * 16 + ((l >> 4) << 2) + r;
        int col = wn + j * 16 + (l & 15);
        float v = eluf_(acc1[i][j][r] + b2g[fb + col]);
        unsigned off = ((unsigned)(m * 512 + col * 2)) ^ ((unsigned)(m & 7) << 4);
        *(bf16*)(sm + off) = (bf16)v;
      }
  __syncthreads();

  floatx4 accO[2][4], accG[2][4];
  #pragma unroll
  for (int i = 0; i < 2; ++i)
    #pragma unroll
    for (int j = 0; j < 4; ++j)
      #pragma unroll
      for (int r = 0; r < 4; ++r) { accO[i][j][r] = 0.f; accG[i][j][r] = 0.f; }
  const bf16* woT = svT + ((size_t)128 + f) * 65536;
  const bf16* wgT = svT + ((size_t)256 + f) * 65536;
  for (int ks = 0; ks < 4; ++ks) {
    __syncthreads();
    stageB(woT, ks);
    __syncthreads();
    #pragma unroll
    for (int kk = 0; kk < 64; kk += 32) {
      int kloc = kk + kb;
      bf16x8 a[2], b[4];
      #pragma unroll
      for (int i = 0; i < 2; ++i) {
        int m = wm + i * 16 + row;
        unsigned off = ((unsigned)(m * 512 + (ks * 64 + kloc) * 2)) ^ ((unsigned)(m & 7) << 4);
        a[i] = *(const bf16x8*)(sm + off);
      }
      #pragma unroll
      for (int j = 0; j < 4; ++j) {
        int n = wn + j * 16 + row;
        unsigned off = 32768u + (((unsigned)(n * 128 + kloc * 2)) ^ ((unsigned)(n & 7) << 4));
        b[j] = *(const bf16x8*)(sm + off);
      }
      #pragma unroll
      for (int i = 0; i < 2; ++i)
        #pragma unroll
        for (int j = 0; j < 4; ++j)
          accO[i][j] = MFMA16(a[i], b[j], accO[i][j]);
    }
  }
  for (int ks = 0; ks < 4; ++ks) {
    __syncthreads();
    stageB(wgT, ks);
    __syncthreads();
    #pragma unroll
    for (int kk = 0; kk < 64; kk += 32) {
      int kloc = kk + kb;
      bf16x8 a[2], b[4];
      #pragma unroll
      for (int i = 0; i < 2; ++i) {
        int m = wm + i * 16 + row;
        unsigned off = ((unsigned)(m * 512 + (ks * 64 + kloc) * 2)) ^ ((unsigned)(m & 7) << 4);
        a[i] = *(const bf16x8*)(sm + off);
      }
      #pragma unroll
      for (int j = 0; j < 4; ++j) {
        int n = wn + j * 16 + row;
        unsigned off = 32768u + (((unsigned)(n * 128 + kloc * 2)) ^ ((unsigned)(n & 7) << 4));
        b[j] = *(const bf16x8*)(sm + off);
      }
      #pragma unroll
      for (int i = 0; i < 2; ++i)
        #pragma unroll
        for (int j = 0; j < 4; ++j)
          accG[i][j] = MFMA16(a[i], b[j], accG[i][j]);
    }
  }
  __syncthreads();
  {
    float xm[2][4];
    #pragma unroll
    for (int i = 0; i < 2; ++i)
      #pragma unroll
      for (int r = 0; r < 4; ++r) {
        int m = wm + i * 16 + ((l >> 4) << 2) + r;
        xm[i][r] = (float)xT[(size_t)f * 1024 + tile * 64 + m];
      }
    #pragma unroll
    for (int i = 0; i < 2; ++i)
      #pragma unroll
      for (int j = 0; j < 4; ++j)
        #pragma unroll
        for (int r = 0; r < 4; ++r) {
          int m = wm + i * 16 + ((l >> 4) << 2) + r;
          int col = wn + j * 16 + (l & 15);
          float vg = sigmf_(accG[i][j][r] + bgg[fb + col]);
          float vo = accO[i][j][r] + bog[fb + col];
          float pre = vg * vo + xm[i][r] * swg[fb + col] + sbg[fb + col];
          unsigned off = ((unsigned)(m * 512 + col * 2)) ^ ((unsigned)(m & 7) << 4);
          *(bf16*)(sm + off) = (bf16)pre;
        }
  }
  __syncthreads();
  {
    int m = tid >> 3, q = tid & 7;
    float vals[32];
    float s = 0.f, s2 = 0.f;
    #pragma unroll
    for (int i = 0; i < 4; ++i) {
      unsigned off = ((unsigned)(m * 512 + (q * 32 + i * 8) * 2)) ^ ((unsigned)(m & 7) << 4);
      bf16x8 hv = *(const bf16x8*)(sm + off);
      #pragma unroll
      for (int j = 0; j < 8; ++j) {
        float x = (float)hv[j];
        vals[i * 8 + j] = x; s += x; s2 += x * x;
      }
    }
    s += __shfl_xor(s, 1, 64);  s += __shfl_xor(s, 2, 64);  s += __shfl_xor(s, 4, 64);
    s2 += __shfl_xor(s2, 1, 64); s2 += __shfl_xor(s2, 2, 64); s2 += __shfl_xor(s2, 4, 64);
    float mean = s * (1.f / 256.f);
    float var = s2 * (1.f / 256.f) - mean * mean;
    float rs = rsqrtf(var + 1e-5f);
    bf16* dst = vbuf + ((size_t)fl * 1024 + tile * 64 + m) * 256 + q * 32;
    #pragma unroll
    for (int i = 0; i < 4; ++i) {
      int c = q * 32 + i * 8;
      float4 g0 = *(const float4*)(lngg + fb + c);
      float4 g1 = *(const float4*)(lngg + fb + c + 4);
      float4 bb0 = *(const float4*)(lnbg + fb + c);
      float4 bb1 = *(const float4*)(lnbg + fb + c + 4);
      bf16x8 ov;
      ov[0] = (bf16)((vals[i * 8 + 0] - mean) * rs * g0.x + bb0.x);
      ov[1] = (bf16)((vals[i * 8 + 1] - mean) * rs * g0.y + bb0.y);
      ov[2] = (bf16)((vals[i * 8 + 2] - mean) * rs * g0.z + bb0.z);
      ov[3] = (bf16)((vals[i * 8 + 3] - mean) * rs * g0.w + bb0.w);
      ov[4] = (bf16)((vals[i * 8 + 4] - mean) * rs * g1.x + bb1.x);
      ov[5] = (bf16)((vals[i * 8 + 5] - mean) * rs * g1.y + bb1.y);
      ov[6] = (bf16)((vals[i * 8 + 6] - mean) * rs * g1.z + bb1.z);
      ov[7] = (bf16)((vals[i * 8 + 7] - mean) * rs * g1.w + bb1.w);
      *(bf16x8*)(dst + i * 8) = ov;
    }
  }
}

// ---------------------------------------------------------------------------
// sel reduce: feats[m][h] (+=) sum_f v[f][m][h]*sw[m][f] (+pos_enc at end)
// ---------------------------------------------------------------------------
__global__ void __launch_bounds__(256, 4)
selreduce_kernel(const bf16* __restrict__ vbuf, const float* __restrict__ sw,
                 const float* __restrict__ pos, float* __restrict__ feats,
                 int f0, int FC, int flags)
{
  const int tid = threadIdx.x;
  const int m = blockIdx.x * 4 + (tid >> 6);
  const int hh = (tid & 63) * 4;
  float a0, a1, a2, a3;
  if (flags & 1) { a0 = a1 = a2 = a3 = 0.f; }
  else {
    float4 v = *(const float4*)(feats + (size_t)m * 256 + hh);
    a0 = v.x; a1 = v.y; a2 = v.z; a3 = v.w;
  }
  for (int fi = 0; fi < FC; ++fi) {
    float wgt = sw[(size_t)m * 128 + f0 + fi];
    bf16x4 v = *(const bf16x4*)(vbuf + ((size_t)fi * 1024 + m) * 256 + hh);
    a0 += wgt * (float)v[0]; a1 += wgt * (float)v[1];
    a2 += wgt * (float)v[2]; a3 += wgt * (float)v[3];
  }
  if (flags & 2) {
    float4 p = *(const float4*)(pos + (size_t)(m & 127) * 256 + hh);
    a0 += p.x; a1 += p.y; a2 += p.z; a3 += p.w;
  }
  float4 o; o.x = a0; o.y = a1; o.z = a2; o.w = a3;
  *(float4*)(feats + (size_t)m * 256 + hh) = o;
}

// ---------------------------------------------------------------------------
// LSTM v3 (proven, deterministic, 573us): unchanged.
// ---------------------------------------------------------------------------
__global__ void __launch_bounds__(256, 1)
lstm_mfma(const bf16* __restrict__ wl, const float* __restrict__ xpre0,
          const float* __restrict__ b0a, const float* __restrict__ b0b,
          const float* __restrict__ b1a, const float* __restrict__ b1b,
          bf16* __restrict__ h0seq, bf16* __restrict__ h1seq,
          float* __restrict__ aseq, unsigned* __restrict__ ctr)
{
  __shared__ float gbuf[4][16][8];
  const int tid = threadIdx.x;
  const int l = tid & 63, w = tid >> 6;
  const int layer = blockIdx.x >> 4, U = (blockIdx.x & 15) * 16;
  const int row = w * 256 + U + (l & 15);
  const int ko = (l >> 4) * 8;
  const bf16* whh = wl + (size_t)(layer ? 3 : 1) * 262144 + (size_t)row * 256;
  const bf16* wih1 = wl + (size_t)2 * 262144 + (size_t)row * 256;
  bf16x8 bw[8], bx[8];
  #pragma unroll
  for (int kt = 0; kt < 8; ++kt) bw[kt] = *(const bf16x8*)(whh + kt * 32 + ko);
  if (layer) {
    #pragma unroll
    for (int kt = 0; kt < 8; ++kt) bx[kt] = *(const bf16x8*)(wih1 + kt * 32 + ko);
  }
  const float bsum = layer ? (b1a[row] + b1b[row]) : (b0a[row] + b0b[row]);
  bf16* hs = layer ? h1seq : h0seq;
  unsigned* c0 = ctr;
  unsigned* c1 = ctr + 128;
  unsigned* cs = layer ? c1 : c0;
  float cstate = 0.f;
  const int au = tid >> 3, ab = tid & 7;

  for (int t = 0; t < 128; ++t) {
    float xp[4] = {0.f, 0.f, 0.f, 0.f};
    if (!layer && (l >> 4) < 2) {
      #pragma unroll
      for (int r = 0; r < 4; ++r) {
        int bb = (l >> 4) * 4 + r;
        xp[r] = xpre0[((size_t)((bb << 7) | t)) * 1024 + row];
      }
    }
    if (tid == 0) {
      if (layer == 0) {
        if (t > 0)
          while (__hip_atomic_load(c0 + t - 1, __ATOMIC_ACQUIRE, __HIP_MEMORY_SCOPE_AGENT) < 16u)
            __builtin_amdgcn_s_sleep(2);
      } else {
        while (__hip_atomic_load(c0 + t, __ATOMIC_ACQUIRE, __HIP_MEMORY_SCOPE_AGENT) < 16u)
          __builtin_amdgcn_s_sleep(2);
        if (t > 0)
          while (__hip_atomic_load(c1 + t - 1, __ATOMIC_ACQUIRE, __HIP_MEMORY_SCOPE_AGENT) < 16u)
            __builtin_amdgcn_s_sleep(2);
      }
    }
    __syncthreads();
    floatx4 acc; acc[0] = acc[1] = acc[2] = acc[3] = 0.f;
    if (t > 0) {
      const bf16* hp = hs + (size_t)(t - 1) * 4096 + (size_t)(l & 15) * 256 + ko;
      #pragma unroll
      for (int kt = 0; kt < 8; ++kt)
        acc = MFMA16(*(const bf16x8*)(hp + kt * 32), bw[kt], acc);
    }
    if (layer) {
      const bf16* hp = h0seq + (size_t)t * 4096 + (size_t)(l & 15) * 256 + ko;
      #pragma unroll
      for (int kt = 0; kt < 8; ++kt)
        acc = MFMA16(*(const bf16x8*)(hp + kt * 32), bx[kt], acc);
    }
    if ((l >> 4) < 2) {
      #pragma unroll
      for (int r = 0; r < 4; ++r) {
        int bb = (l >> 4) * 4 + r;
        gbuf[w][l & 15][bb] = acc[r] + bsum + xp[r];
      }
    }
    __syncthreads();
    if (tid < 128) {
      float gi = gbuf[0][au][ab], gf = gbuf[1][au][ab];
      float gg = gbuf[2][au][ab], go = gbuf[3][au][ab];
      cstate = sigmf_(gf) * cstate + sigmf_(gi) * tanhf(gg);
      float h = sigmf_(go) * tanhf(cstate);
      hs[(size_t)t * 4096 + (size_t)ab * 256 + U + au] = (bf16)h;
      if (layer) aseq[((size_t)((ab << 7) | t)) * 256 + U + au] = h;
    }
    __syncthreads();
    if (tid == 0) {
      __threadfence();
      __hip_atomic_fetch_add(cs + t, 1u, __ATOMIC_RELEASE, __HIP_MEMORY_SCOPE_AGENT);
    }
  }
}

// ---------------------------------------------------------------------------
// Attention core per (b,h): scores->softmax->ctx (fp32, logits tiny).
// ---------------------------------------------------------------------------
__global__ void __launch_bounds__(256, 2)
attn_kernel(const float* __restrict__ qkv, float* __restrict__ ctxo)
{
  __shared__ float Kb[128][40];
  __shared__ float Vb[128][40];
  const int tid = threadIdx.x;
  const int b = blockIdx.x >> 3, h = blockIdx.x & 7;
  const int s = tid >> 1, half = tid & 1;
  {
    const float* kr = qkv + ((size_t)(b * 128 + s)) * 768 + 256 + h * 32 + half * 16;
    #pragma unroll
    for (int i = 0; i < 4; ++i) {
      *(float4*)&Kb[s][half * 16 + i * 4] = *(const float4*)(kr + i * 4);
      *(float4*)&Vb[s][half * 16 + i * 4] = *(const float4*)(kr + 256 + i * 4);
    }
  }
  float q[32];
  {
    const float* qr = qkv + ((size_t)(b * 128 + s)) * 768 + h * 32;
    #pragma unroll
    for (int i = 0; i < 8; ++i) {
      float4 v = *(const float4*)(qr + i * 4);
      q[i * 4 + 0] = v.x; q[i * 4 + 1] = v.y; q[i * 4 + 2] = v.z; q[i * 4 + 3] = v.w;
    }
  }
  __syncthreads();
  const float scale = 0.17677669529663687f;
  float se = 0.f;
  float ca[32];
  #pragma unroll
  for (int i = 0; i < 32; ++i) ca[i] = 0.f;
  for (int c0 = 0; c0 < 64; ++c0) {
    int c = half * 64 + c0;
    float d = 0.f;
    #pragma unroll
    for (int i = 0; i < 32; ++i) d += q[i] * Kb[c][i];
    float e = expf(d * scale);
    se += e;
    #pragma unroll
    for (int i = 0; i < 32; ++i) ca[i] += e * Vb[c][i];
  }
  se += __shfl_xor(se, 1, 64);
  #pragma unroll
  for (int i = 0; i < 32; ++i) ca[i] += __shfl_xor(ca[i], 1, 64);
  if (half == 0) {
    float inv = 1.f / se;
    float* outp = ctxo + ((size_t)(b * 128 + s)) * 256 + h * 32;
    #pragma unroll
    for (int i = 0; i < 32; i += 4) {
      float4 v; v.x = ca[i] * inv; v.y = ca[i + 1] * inv; v.z = ca[i + 2] * inv; v.w = ca[i + 3] * inv;
      *(float4*)(outp + i) = v;
    }
  }
}

// LN over 256 cols; optional fp32 mirror (final layer -> d_out 'a')
__global__ void __launch_bounds__(256, 4)
ln_kernel(const float* __restrict__ in, const float* __restrict__ g,
          const float* __restrict__ bta, float* __restrict__ out,
          float* __restrict__ mirror)
{
  const int tid = threadIdx.x;
  const int m = blockIdx.x * 4 + (tid >> 6);
  const int l = tid & 63;
  float4 v = *(const float4*)(in + (size_t)m * 256 + l * 4);
  float s = v.x + v.y + v.z + v.w;
  float s2 = v.x * v.x + v.y * v.y + v.z * v.z + v.w * v.w;
  #pragma unroll
  for (int k = 1; k < 64; k <<= 1) { s += __shfl_xor(s, k, 64); s2 += __shfl_xor(s2, k, 64); }
  float mean = s * (1.f / 256.f);
  float var = s2 * (1.f / 256.f) - mean * mean;
  float rs = rsqrtf(var + 1e-5f);
  float4 gg = *(const float4*)(g + l * 4);
  float4 bb = *(const float4*)(bta + l * 4);
  float4 o;
  o.x = (v.x - mean) * rs * gg.x + bb.x;
  o.y = (v.y - mean) * rs * gg.y + bb.y;
  o.z = (v.z - mean) * rs * gg.z + bb.z;
  o.w = (v.w - mean) * rs * gg.w + bb.w;
  *(float4*)(out + (size_t)m * 256 + l * 4) = o;
  if (mirror) *(float4*)(mirror + (size_t)m * 256 + l * 4) = o;
}

__global__ void __launch_bounds__(256)
gctx_kernel(const float* __restrict__ a, float* __restrict__ g)
{
  int b = blockIdx.x, hh = threadIdx.x;
  float s = 0.f;
  for (int ss = 0; ss < 128; ++ss) s += a[((size_t)b * 128 + ss) * 256 + hh];
  g[b * 256 + hh] = s * (1.f / 128.f);
}

__global__ void __launch_bounds__(256, 1)
head_kernel(const float* __restrict__ g, const float* __restrict__ w1,
            const float* __restrict__ b1, const float* __restrict__ w2,
            const float* __restrict__ b2, const float* __restrict__ qw,
            const float* __restrict__ qb, float* __restrict__ dout)
{
  __shared__ float hid[8][128];
  const int tid = threadIdx.x;
  for (int o = tid; o < 1024; o += 256) {
    int b = o >> 7, j = o & 127;
    float s = b1[j];
    for (int k = 0; k < 256; ++k) s += g[b * 256 + k] * w1[(size_t)k * 128 + j];
    hid[b][j] = s > 0.f ? s : 0.f;
  }
  __syncthreads();
  if (tid < 192) {
    int b = tid / 24, j = tid - b * 24;
    float s = b2[j];
    for (int k = 0; k < 128; ++k) s += hid[b][k] * w2[(size_t)k * 24 + j];
    dout[b * 24 + j] = s;
  }
  for (int o = tid; o < 576; o += 256) {
    int qi = o / 192, rr = o - qi * 192, b = rr / 24, j = rr - b * 24;
    float s = qb[qi * 24 + j];
    for (int k = 0; k < 256; ++k) s += g[b * 256 + k] * qw[((size_t)qi * 256 + k) * 24 + j];
    dout[192 + o] = s;
  }
}

// ---------------------------------------------------------------------------
extern "C" void kernel_launch(void* const* d_in, const int* in_sizes, int n_in,
                              void* d_out, int out_size, void* d_ws, size_t ws_size,
                              hipStream_t stream)
{
  (void)in_sizes; (void)n_in; (void)out_size;
  auto F = [&](int i) { return (const float*)d_in[i]; };
  char* ws = (char*)d_ws;
  size_t o = 0;
  auto alloc = [&](size_t b) { size_t r = o; o = (o + b + 255) & ~(size_t)255; return r; };

  size_t svT_o  = alloc((size_t)3 * 128 * 65536 * 2);
  size_t wl_o   = alloc((size_t)4 * 262144 * 2);
  size_t qkvT_o = alloc((size_t)4 * 196608 * 2);
  size_t woT_o  = alloc((size_t)4 * 65536 * 2);
  size_t w1T_o  = alloc(256 * 128 * 2);
  size_t w2T_o  = alloc(256 * 256 * 2);
  size_t goT_o  = alloc(256 * 256 * 2);
  size_t swT_o  = alloc(128 * 128 * 2);
  size_t xT_o   = alloc(128 * 1024 * 2);
  size_t h_o    = alloc((size_t)1024 * 256 * 4);
  size_t h2_o   = alloc((size_t)1024 * 256 * 4);
  size_t go_o   = alloc((size_t)1024 * 256 * 4);
  size_t skip_o = alloc((size_t)1024 * 128 * 4);
  size_t feat_o = alloc((size_t)1024 * 256 * 4);
  size_t xpre_o = alloc((size_t)1024 * 1024 * 4);
  size_t qkv_o  = alloc((size_t)1024 * 768 * 4);
  size_t ctx_o  = alloc((size_t)1024 * 256 * 4);
  size_t pre_o  = alloc((size_t)1024 * 256 * 4);
  size_t aA_o   = alloc((size_t)1024 * 256 * 4);
  size_t aB_o   = alloc((size_t)1024 * 256 * 4);
  size_t gctx_o = alloc(8 * 256 * 4);
  size_t z_o    = alloc((size_t)2 * 1048576 + 1024);
  size_t aseq_o = alloc((size_t)1024 * 256 * 4);
  int FC = 128;
  while (FC > 4 && o + (size_t)FC * 1024 * 256 * 2 > ws_size) FC >>= 1;
  size_t vb_o = alloc((size_t)FC * 1024 * 256 * 2);
  if (o > ws_size) return;

  bf16* svTp  = (bf16*)(ws + svT_o);
  bf16* wlp   = (bf16*)(ws + wl_o);
  bf16* qkvTp = (bf16*)(ws + qkvT_o);
  bf16* woTp  = (bf16*)(ws + woT_o);
  bf16* w1Tp  = (bf16*)(ws + w1T_o);
  bf16* w2Tp  = (bf16*)(ws + w2T_o);
  bf16* goTp  = (bf16*)(ws + goT_o);
  bf16* swTp  = (bf16*)(ws + swT_o);
  bf16* xTp   = (bf16*)(ws + xT_o);
  float* hp    = (float*)(ws + h_o);
  float* h2p   = (float*)(ws + h2_o);
  float* gop   = (float*)(ws + go_o);
  float* skipp = (float*)(ws + skip_o);
  float* featp = (float*)(ws + feat_o);
  float* xprep = (float*)(ws + xpre_o);
  float* qkvp  = (float*)(ws + qkv_o);
  float* ctxp  = (float*)(ws + ctx_o);
  float* prep  = (float*)(ws + pre_o);
  float* aAp   = (float*)(ws + aA_o);
  float* aBp   = (float*)(ws + aB_o);
  float* gctxp = (float*)(ws + gctx_o);
  bf16* h0p    = (bf16*)(ws + z_o);
  bf16* h1p    = (bf16*)(ws + z_o + 1048576);
  unsigned* ctrp = (unsigned*)(ws + z_o + 2097152);
  float* aseqp = (float*)(ws + aseq_o);
  bf16* vbp    = (bf16*)(ws + vb_o);

  // d_out FP32: pf@0[192], q10@192, q50@384, q90@576, sw@768[131072], a@131840[262144]
  float* outp  = (float*)d_out;
  float* sw_do = outp + 768;
  float* a_do  = outp + 131840;

  hipMemsetAsync(ws + z_o, 0, 2097152 + 1024, stream);

  // ---- weight prep (every launch) ----
  transpose_sv<<<dim3(16, 384), 256, 0, stream>>>(F(15), F(17), F(19), svTp);
  {
    TJobs tj; int nj = 0;
    auto addj = [&](const float* s, bf16* d, int R, int C) { tj.j[nj].src = s; tj.j[nj].dst = d; tj.j[nj].R = R; tj.j[nj].C = C; ++nj; };
    for (int l = 0; l < 4; ++l) {
      addj(F(34) + (size_t)l * 65536, qkvTp + (size_t)l * 196608, 256, 256);
      addj(F(35) + (size_t)l * 65536, qkvTp + (size_t)l * 196608 + 65536, 256, 256);
      addj(F(36) + (size_t)l * 65536, qkvTp + (size_t)l * 196608 + 131072, 256, 256);
      addj(F(37) + (size_t)l * 65536, woTp + (size_t)l * 65536, 256, 256);
    }
    addj(F(1), w1Tp, 128, 256);
    addj(F(3), w2Tp, 256, 256);
    addj(F(7), goTp, 256, 128);
    addj(F(5), goTp + 128 * 256, 256, 128);
    addj(F(9), swTp, 128, 128);
    addj(F(0), xTp, 1024, 128);
    transpose_misc<<<dim3(32, 22), 256, 0, stream>>>(tj);
  }
  cvt4_kernel<<<1024, 256, 0, stream>>>(F(26), F(27), F(30), F(31), wlp);

  auto gemm = [&](int epi, const float* A, int lda, const bf16* BT, int ldb,
                  float* C, int ldc, int M, int N, int K,
                  const float* b1, const float* b2r) {
    dim3 g(N / 64, M / 128);
    switch (epi) {
      case 0: gemm_bf16<0><<<g, 256, 0, stream>>>(A, lda, BT, ldb, C, ldc, b1, b2r, K); break;
      case 1: gemm_bf16<1><<<g, 256, 0, stream>>>(A, lda, BT, ldb, C, ldc, b1, b2r, K); break;
      case 2: gemm_bf16<2><<<g, 256, 0, stream>>>(A, lda, BT, ldb, C, ldc, b1, b2r, K); break;
      case 3: gemm_bf16<3><<<g, 256, 0, stream>>>(A, lda, BT, ldb, C, ldc, b1, b2r, K); break;
      case 4: gemm_bf16<4><<<g, 256, 0, stream>>>(A, lda, BT, ldb, C, ldc, b1, b2r, K); break;
    }
  };

  // ---- flattened GRN -> variable selection weights ----
  gemm(2, F(0), 128, w1Tp, 128, hp, 256, 1024, 256, 128, F(2), nullptr);
  gemm(2, hp, 256, w2Tp, 256, h2p, 256, 1024, 256, 256, F(4), nullptr);
  gemm(3, h2p, 256, goTp, 256, gop, 256, 1024, 256, 256, F(8), F(6));
  gemm(1, F(0), 128, swTp, 128, skipp, 128, 1024, 128, 128, F(10), nullptr);
  grnflat_sw_kernel<<<256, 256, 0, stream>>>(gop, skipp, F(11), F(12), sw_do);

  // ---- per-variable GRNs ----
  int chunks = 128 / FC;
  for (int c = 0; c < chunks; ++c) {
    pervar_kernel<<<dim3(16, FC), 512, 0, stream>>>(
        xTp, svTp, F(13), F(14), F(16), F(18), F(20), F(21), F(22), F(23), F(24),
        vbp, c * FC);
    selreduce_kernel<<<256, 256, 0, stream>>>(
        vbp, sw_do, F(25), featp, c * FC, FC,
        (c == 0 ? 1 : 0) | (c == chunks - 1 ? 2 : 0));
  }

  // ---- LSTM ----
  gemm(0, featp, 256, wlp, 256, xprep, 1024, 1024, 1024, 256, nullptr, nullptr);
  lstm_mfma<<<32, 256, 0, stream>>>(wlp, xprep, F(28), F(29), F(32), F(33),
                                    h0p, h1p, aseqp, ctrp);

  // ---- attention layers ----
  const float* ain = aseqp;
  float* louts[4] = {aAp, aBp, aAp, aBp};
  for (int l = 0; l < 4; ++l) {
    gemm(0, ain, 256, qkvTp + (size_t)l * 196608, 256, qkvp, 768, 1024, 768, 256, nullptr, nullptr);
    attn_kernel<<<64, 256, 0, stream>>>(qkvp, ctxp);
    gemm(4, ctxp, 256, woTp + (size_t)l * 65536, 256, prep, 256, 1024, 256, 256,
         F(38) + (size_t)l * 256, ain);
    ln_kernel<<<256, 256, 0, stream>>>(prep, F(39) + (size_t)l * 256, F(40) + (size_t)l * 256,
                                       louts[l], l == 3 ? a_do : (float*)nullptr);
    ain = louts[l];
  }

  // ---- heads ----
  gctx_kernel<<<8, 256, 0, stream>>>(aBp, gctxp);
  head_kernel<<<1, 256, 0, stream>>>(gctxp, F(41), F(42), F(43), F(44), F(45), F(46), outp);
}